// Round 7
// baseline (525.683 us; speedup 1.0000x reference)
//
#include <hip/hip_runtime.h>
#include <hip/hip_bf16.h>

typedef __hip_bfloat16 bf16;
typedef __attribute__((ext_vector_type(8))) short bf16x8;
typedef __attribute__((ext_vector_type(4))) float f32x4;

#define HEADS 16
#define HDIM  64
#define DIM   1024
#define SEQ   2048
#define BATCH 4
#define BS    (BATCH * SEQ)   // 8192
#define SCALE 0.125f          // 1/sqrt(64)
#define CS    0.1803368801111f  // SCALE * log2(e): softmax in exp2 domain
#define QBLK  128

#define EXP2F(x) __builtin_amdgcn_exp2f(x)
#define MFMA16(a, b, c) __builtin_amdgcn_mfma_f32_16x16x32_bf16(a, b, c, 0, 0, 0)

__device__ __forceinline__ void gload_lds16(const void* g, void* l) {
    __builtin_amdgcn_global_load_lds(
        (const __attribute__((address_space(1))) void*)g,
        (__attribute__((address_space(3))) void*)l, 16, 0, 0);
}

__device__ __forceinline__ void cvt8(const float* __restrict__ src, bf16* __restrict__ dst,
                                     size_t i)
{
    float4 f0 = *(const float4*)&src[i];
    float4 f1 = *(const float4*)&src[i + 4];
    union { bf16 h[8]; uint4 u; } pk;
    pk.h[0] = __float2bfloat16(f0.x); pk.h[1] = __float2bfloat16(f0.y);
    pk.h[2] = __float2bfloat16(f0.z); pk.h[3] = __float2bfloat16(f0.w);
    pk.h[4] = __float2bfloat16(f1.x); pk.h[5] = __float2bfloat16(f1.y);
    pk.h[6] = __float2bfloat16(f1.z); pk.h[7] = __float2bfloat16(f1.w);
    *(uint4*)&dst[i] = pk.u;
}

// ---------------------------------------------------------------------------
// Kernel 0a: fp32 -> bf16 for Q,K,V,Wq,Wk,Wv (consumed by proj, which
// completes BEFORE attn overwrites the scratch region in weights-tail).
// ---------------------------------------------------------------------------
__global__ __launch_bounds__(256) void cvt_kernel(
    const float* __restrict__ Q, const float* __restrict__ K, const float* __restrict__ V,
    const float* __restrict__ Wq, const float* __restrict__ Wk, const float* __restrict__ Wv,
    bf16* __restrict__ xq, bf16* __restrict__ xk, bf16* __restrict__ xv,
    bf16* __restrict__ wq, bf16* __restrict__ wk, bf16* __restrict__ wv)
{
    const int seg = blockIdx.y;
    const float* src; bf16* dst; size_t n;
    switch (seg) {
        case 0: src = Q;  dst = xq; n = (size_t)BS * DIM;   break;
        case 1: src = K;  dst = xk; n = (size_t)BS * DIM;   break;
        case 2: src = V;  dst = xv; n = (size_t)BS * DIM;   break;
        case 3: src = Wq; dst = wq; n = (size_t)DIM * DIM;  break;
        case 4: src = Wk; dst = wk; n = (size_t)DIM * DIM;  break;
        default: src = Wv; dst = wv; n = (size_t)DIM * DIM; break;
    }
    size_t i = ((size_t)blockIdx.x * 256 + threadIdx.x) * 8;
    if (i >= n) return;
    cvt8(src, dst, i);
}

// Kernel 0b: Wo fp32 -> bf16, launched AFTER attn into the then-dead qws
// region of d_ws (attn is qws's last reader).
__global__ __launch_bounds__(256) void cvt_wo_kernel(
    const float* __restrict__ Wo, bf16* __restrict__ wo)
{
    size_t i = ((size_t)blockIdx.x * 256 + threadIdx.x) * 8;
    cvt8(Wo, wo, i);
}

// ---------------------------------------------------------------------------
// MFMA GEMM core: 128x128 C-tile of A (row-major, ld=DIM) x B^T (B row-major,
// ld=DIM), K=DIM.  Fragment-linear LDS (see round-2 comment).
// ---------------------------------------------------------------------------
__device__ __forceinline__ void mfma_core_1024(
    const bf16* __restrict__ A, const bf16* __restrict__ B,
    int m0, int n0, bf16* sA, f32x4 acc[4][4])
{
    const int tid = threadIdx.x, lane = tid & 63, wave = tid >> 6;
    const int l15 = lane & 15, lg = lane >> 4;
    const int wr = wave >> 1, wc = wave & 1;
    bf16* sB = sA + 16 * 512;

    const bf16* gsrc = (wave < 2) ? A : B;
    const int   gm0  = (wave < 2) ? m0 : n0;
    bf16*       sdst = (wave < 2) ? sA : sB;
    const int   wv2  = wave & 1;

#define STAGE(k0_) { \
    _Pragma("unroll") for (int u = 0; u < 8; ++u) { \
        const int c = wv2 * 8 + u; \
        const int mg = c >> 1, s = c & 1; \
        gload_lds16(gsrc + (size_t)(gm0 + mg * 16 + l15) * DIM + (k0_) + s * 32 + lg * 8, \
                    sdst + c * 512); \
    } }

    STAGE(0);
#pragma unroll 1
    for (int t = 0; t < DIM / 64; ++t) {
        __syncthreads();
#pragma unroll
        for (int s = 0; s < 2; ++s) {
            bf16x8 af[4], bfr[4];
#pragma unroll
            for (int i = 0; i < 4; ++i)
                af[i] = *(const bf16x8*)(sA + ((wr * 4 + i) * 2 + s) * 512 + lane * 8);
#pragma unroll
            for (int j = 0; j < 4; ++j)
                bfr[j] = *(const bf16x8*)(sB + ((wc * 4 + j) * 2 + s) * 512 + lane * 8);
#pragma unroll
            for (int i = 0; i < 4; ++i)
#pragma unroll
                for (int j = 0; j < 4; ++j)
                    acc[i][j] = MFMA16(af[i], bfr[j], acc[i][j]);
        }
        __syncthreads();
        if (t < DIM / 64 - 1) STAGE((t + 1) * 64);
    }
#undef STAGE
}

// ---------------------------------------------------------------------------
// Kernel 1: QKV projections via MFMA.  Q/K out (B,H,S,D); V out (B,H,D,S).
// ---------------------------------------------------------------------------
__global__ __launch_bounds__(256) void proj_mfma_kernel(
    const bf16* __restrict__ Xq, const bf16* __restrict__ Xk, const bf16* __restrict__ Xv,
    const bf16* __restrict__ Wq, const bf16* __restrict__ Wk, const bf16* __restrict__ Wv,
    bf16* __restrict__ qo, bf16* __restrict__ ko, bf16* __restrict__ vo)
{
    __shared__ alignas(16) bf16 smem[16384];   // 32 KB
    const int z = blockIdx.z;
    const bf16* X = z == 0 ? Xq : z == 1 ? Xk : Xv;
    const bf16* W = z == 0 ? Wq : z == 1 ? Wk : Wv;
    const int m0 = blockIdx.y * 128, n0 = blockIdx.x * 128;
    f32x4 acc[4][4] = {};
    mfma_core_1024(X, W, m0, n0, smem, acc);

    const int tid = threadIdx.x, lane = tid & 63, wave = tid >> 6;
    const int l15 = lane & 15, lg = lane >> 4, wr = wave >> 1, wc = wave & 1;
    const int h = blockIdx.x * 2 + wc;     // 128-wide n-tile spans 2 heads

    if (z != 2) {
        bf16* O = z == 0 ? qo : ko;
#pragma unroll
        for (int i = 0; i < 4; ++i)
#pragma unroll
            for (int r = 0; r < 4; ++r) {
                int m = m0 + wr * 64 + i * 16 + lg * 4 + r;
                int bb = m >> 11, ss = m & (SEQ - 1);
                size_t base = ((size_t)(bb * HEADS + h) * SEQ + ss) * HDIM;
#pragma unroll
                for (int j = 0; j < 4; ++j)
                    O[base + j * 16 + l15] = __float2bfloat16(acc[i][j][r]);
            }
    } else {
#pragma unroll
        for (int i = 0; i < 4; ++i) {
            int s0 = m0 + wr * 64 + i * 16 + lg * 4;
            int bb = s0 >> 11, ss = s0 & (SEQ - 1);
#pragma unroll
            for (int j = 0; j < 4; ++j) {
                int d = j * 16 + l15;
                union { bf16 h4[4]; uint2 u; } pk;
#pragma unroll
                for (int r = 0; r < 4; ++r) pk.h4[r] = __float2bfloat16(acc[i][j][r]);
                *(uint2*)&vo[((size_t)(bb * HEADS + h) * HDIM + d) * SEQ + ss] = pk.u;
            }
        }
    }
}

// ---------------------------------------------------------------------------
// Kernel 2: causal attention, MFMA bf16, swapped QK^T, QBLK=128 (8 waves).
// Wave w owns q rows [q0+16w, q0+16w+16).  Waves 0-3 stage K tiles, waves
// 4-7 stage V tiles (pass 2).  Per-wave skip of fully-masked diag tiles.
// ---------------------------------------------------------------------------
__global__ __launch_bounds__(512) void attn_kernel(
    const bf16* __restrict__ qws, const bf16* __restrict__ kws, const bf16* __restrict__ vtws,
    float* __restrict__ weights, bf16* __restrict__ attn_out)
{
    __shared__ alignas(16) bf16 Ks[4096];   // 64k x 64d, 8 fragment chunks
    __shared__ alignas(16) bf16 Vs[4096];   // 64d x 64k, 8 fragment chunks
    __shared__ alignas(16) bf16 Ps[8192];   // 8 waves x 1024 (wave-private)

    const int tid  = threadIdx.x;
    const int lane = tid & 63;
    const int wave = tid >> 6;              // 0..7
    const int l15  = lane & 15;
    const int lg   = lane >> 4;
    const int qt = (int)gridDim.x - 1 - (int)blockIdx.x;  // heavy blocks first
    const int h  = blockIdx.y, b = blockIdx.z;
    const int bh = b * HEADS + h;
    const int q0 = qt * QBLK;
    const int qloc = 16 * wave + l15;       // this lane's q row within tile
    const int qmaxw = q0 + 16 * wave + 15;  // wave's max q row (global)
    const int nkt = 2 * qt + 2;             // 64-wide k-tiles to process

    const bf16* qbase = qws + (size_t)bh * SEQ * HDIM;
    const bf16* kbase = kws + (size_t)bh * SEQ * HDIM;
    const bf16* vbase = vtws + (size_t)bh * HDIM * SEQ;

    const bool stagek = wave < 4;
    const int  sw = wave & 3;               // staging row-group

    bf16x8 qa0, qa1;
    {
        const bf16* qp = qbase + (size_t)(q0 + qloc) * HDIM + lg * 8;
        qa0 = *(const bf16x8*)qp;
        qa1 = *(const bf16x8*)(qp + 32);
    }

#define LOADK(kt_, r0, r1) { \
    const bf16* rp = kbase + (size_t)((kt_) * 64 + 16 * sw + l15) * HDIM + lg * 8; \
    r0 = *(const uint4*)rp; r1 = *(const uint4*)(rp + 32); }
#define STOREK(r0, r1) { \
    *(uint4*)&Ks[((sw * 2 + 0) * 64 + lane) * 8] = r0; \
    *(uint4*)&Ks[((sw * 2 + 1) * 64 + lane) * 8] = r1; }
#define LOADV(kt_, r0, r1) { \
    const bf16* rp = vbase + (size_t)(16 * sw + l15) * SEQ + (kt_) * 64 + lg * 8; \
    r0 = *(const uint4*)rp; r1 = *(const uint4*)(rp + 32); }
#define STOREV(r0, r1) { \
    *(uint4*)&Vs[((sw * 2 + 0) * 64 + lane) * 8] = r0; \
    *(uint4*)&Vs[((sw * 2 + 1) * 64 + lane) * 8] = r1; }
// swapped: A = K chunk, B = Q  ->  acc[ct][r] = S[q=l15][k=ct*16+lg*4+r]
#define QKT(acc_) { \
    _Pragma("unroll") \
    for (int ct = 0; ct < 4; ++ct) { \
        bf16x8 b0 = *(const bf16x8*)&Ks[((ct * 2 + 0) * 64 + lane) * 8]; \
        bf16x8 b1 = *(const bf16x8*)&Ks[((ct * 2 + 1) * 64 + lane) * 8]; \
        acc_[ct] = MFMA16(b0, qa0, acc_[ct]); \
        acc_[ct] = MFMA16(b1, qa1, acc_[ct]); \
    } }

    // ---- pass 1: online row max / sum-exp2 (scalar per-lane stats) ----
    float m_run = -1e30f;
    float l_run = 0.f;

    if (stagek) {
        uint4 k0, k1;
        LOADK(0, k0, k1);
        STOREK(k0, k1);
    }
    for (int kt = 0; kt < nkt; ++kt) {
        __syncthreads();                    // staged K visible
        const bool active = (kt * 64 <= qmaxw);
        const bool more = kt + 1 < nkt;
        uint4 nk0, nk1;
        if (active) {
            f32x4 acc[4] = {};
            QKT(acc);
            if (stagek && more) LOADK(kt + 1, nk0, nk1);
            const bool diag = (kt * 64 + 63 > qmaxw - 15);  // tile crosses diag
            float t[4][4];
#pragma unroll
            for (int ct = 0; ct < 4; ++ct)
#pragma unroll
                for (int r = 0; r < 4; ++r) {
                    float v = acc[ct][r] * CS;
                    if (diag && (kt * 64 + ct * 16 + lg * 4 + r > q0 + qloc)) v = -1e30f;
                    t[ct][r] = v;
                }
            float tm = -1e30f;
#pragma unroll
            for (int ct = 0; ct < 4; ++ct)
#pragma unroll
                for (int r = 0; r < 4; ++r) tm = fmaxf(tm, t[ct][r]);
            tm = fmaxf(tm, __shfl_xor(tm, 16));
            tm = fmaxf(tm, __shfl_xor(tm, 32));
            float mn = fmaxf(m_run, tm);
            float ps = 0.f;
#pragma unroll
            for (int ct = 0; ct < 4; ++ct)
#pragma unroll
                for (int r = 0; r < 4; ++r) ps += EXP2F(t[ct][r] - mn);
            ps += __shfl_xor(ps, 16);
            ps += __shfl_xor(ps, 32);
            l_run = l_run * EXP2F(m_run - mn) + ps;
            m_run = mn;
        } else {
            if (stagek && more) LOADK(kt + 1, nk0, nk1);
        }
        __syncthreads();                    // all waves done reading Ks
        if (stagek && more) STOREK(nk0, nk1);
    }

    const float il = 1.0f / l_run;

    // ---- pass 2: weights + PV ----
    if (stagek) {
        uint4 k0, k1;
        LOADK(0, k0, k1);
        STOREK(k0, k1);
    } else {
        uint4 v0, v1;
        LOADV(0, v0, v1);
        STOREV(v0, v1);
    }
    f32x4 oacc[4] = {};
    const size_t wrow = ((size_t)bh * SEQ + q0 + qloc) * SEQ;

    for (int kt = 0; kt < nkt; ++kt) {
        __syncthreads();                    // staged K,V visible
        const bool active = (kt * 64 <= qmaxw);
        const bool more = kt + 1 < nkt;
        uint4 n0, n1;
        if (active) {
            f32x4 acc[4] = {};
            QKT(acc);
            if (more) { if (stagek) LOADK(kt + 1, n0, n1) else LOADV(kt + 1, n0, n1) }
            const bool diag = (kt * 64 + 63 > qmaxw - 15);
#pragma unroll
            for (int ct = 0; ct < 4; ++ct) {
                f32x4 w4;
                union { bf16 h4[4]; uint2 u; } pk;
#pragma unroll
                for (int r = 0; r < 4; ++r) {
                    float v = acc[ct][r] * CS;
                    if (diag && (kt * 64 + ct * 16 + lg * 4 + r > q0 + qloc)) v = -1e30f;
                    float w = EXP2F(v - m_run) * il;
                    w4[r] = w;
                    pk.h4[r] = __float2bfloat16(w);
                }
                __builtin_nontemporal_store(
                    w4, (f32x4*)&weights[wrow + kt * 64 + ct * 16 + lg * 4]);
                // packed P transpose into wave-private LDS (A-fragment layout)
                *(uint2*)&Ps[wave * 1024
                             + (((ct >> 1) * 64 + ((ct & 1) * 2 + (lg >> 1)) * 16 + l15) * 8
                                + (lg & 1) * 4)] = pk.u;
            }
            // PV: Ps is wave-private; compiler orders ds_write -> ds_read.
            bf16x8 pa0 = *(const bf16x8*)&Ps[wave * 1024 + lane * 8];
            bf16x8 pa1 = *(const bf16x8*)&Ps[wave * 1024 + 512 + lane * 8];
#pragma unroll
            for (int td = 0; td < 4; ++td) {
                bf16x8 vb0 = *(const bf16x8*)&Vs[((td * 2 + 0) * 64 + lane) * 8];
                bf16x8 vb1 = *(const bf16x8*)&Vs[((td * 2 + 1) * 64 + lane) * 8];
                oacc[td] = MFMA16(pa0, vb0, oacc[td]);
                oacc[td] = MFMA16(pa1, vb1, oacc[td]);
            }
        } else {
            if (more) { if (stagek) LOADK(kt + 1, n0, n1) else LOADV(kt + 1, n0, n1) }
            const f32x4 z = {0.f, 0.f, 0.f, 0.f};
#pragma unroll
            for (int ct = 0; ct < 4; ++ct)
                __builtin_nontemporal_store(
                    z, (f32x4*)&weights[wrow + kt * 64 + ct * 16 + lg * 4]);
        }
        __syncthreads();                    // all waves done with Ks/Vs
        if (more) { if (stagek) STOREK(n0, n1) else STOREV(n0, n1) }
    }

    // O tile write: (b, s, h*64 + d) bf16  (row q = lg*4+r, col d = td*16+l15)
#pragma unroll
    for (int td = 0; td < 4; ++td)
#pragma unroll
        for (int r = 0; r < 4; ++r) {
            int rowg = q0 + 16 * wave + lg * 4 + r;
            attn_out[((size_t)b * SEQ + rowg) * DIM + h * HDIM + td * 16 + l15]
                = __float2bfloat16(oacc[td][r]);
        }

    // zero-fill masked (upper-triangle) weight columns (streaming NT stores)
    const int zc0 = (qt + 1) * QBLK;
    if (zc0 < SEQ) {
        const int nc4 = (SEQ - zc0) >> 2;
        const size_t base = ((size_t)bh * SEQ + q0) * SEQ + zc0;
        const f32x4 z = {0.f, 0.f, 0.f, 0.f};
        for (int r = 0; r < QBLK; ++r)
            for (int c = tid; c < nc4; c += 512)
                __builtin_nontemporal_store(
                    z, (f32x4*)&weights[base + (size_t)r * SEQ + (size_t)c * 4]);
    }
#undef LOADK
#undef STOREK
#undef LOADV
#undef STOREV
#undef QKT
}

// ---------------------------------------------------------------------------
// Kernel 3: output projection via MFMA, fp32 out + bias.
// ---------------------------------------------------------------------------
__global__ __launch_bounds__(256) void oproj_mfma_kernel(
    const bf16* __restrict__ A, const bf16* __restrict__ Wo,
    const float* __restrict__ bo, float* __restrict__ out)
{
    __shared__ alignas(16) bf16 smem[16384];
    const int m0 = blockIdx.y * 128, n0 = blockIdx.x * 128;
    f32x4 acc[4][4] = {};
    mfma_core_1024(A, Wo, m0, n0, smem, acc);

    const int tid = threadIdx.x, lane = tid & 63, wave = tid >> 6;
    const int l15 = lane & 15, lg = lane >> 4, wr = wave >> 1, wc = wave & 1;
    float bv[4];
#pragma unroll
    for (int j = 0; j < 4; ++j) bv[j] = bo[n0 + wc * 64 + j * 16 + l15];
#pragma unroll
    for (int i = 0; i < 4; ++i)
#pragma unroll
        for (int r = 0; r < 4; ++r) {
            int m = m0 + wr * 64 + i * 16 + lg * 4 + r;
#pragma unroll
            for (int j = 0; j < 4; ++j)
                out[(size_t)m * DIM + n0 + wc * 64 + j * 16 + l15] = acc[i][j][r] + bv[j];
        }
}

// ---------------------------------------------------------------------------
extern "C" void kernel_launch(void* const* d_in, const int* in_sizes, int n_in,
                              void* d_out, int out_size, void* d_ws, size_t ws_size,
                              hipStream_t stream)
{
    const float* Q  = (const float*)d_in[0];
    const float* K  = (const float*)d_in[1];
    const float* V  = (const float*)d_in[2];
    const float* Wq = (const float*)d_in[3];
    const float* Wk = (const float*)d_in[4];
    const float* Wv = (const float*)d_in[5];
    const float* Wo = (const float*)d_in[6];
    const float* bo = (const float*)d_in[7];

    float* out     = (float*)d_out;
    float* weights = out + (size_t)BS * DIM;   // 268,435,456 floats

    // Pre-attn bf16 scratch lives in the TAIL of the weights buffer; its only
    // readers (proj_mfma) complete before attn overwrites all of weights.
    const size_t XN = (size_t)BS * DIM;        // 8,388,608
    const size_t WN = (size_t)DIM * DIM;       // 1,048,576
    const size_t scratch_elems = 3 * XN + 3 * WN;   // bf16 elements
    bf16* cvt = (bf16*)(weights + ((size_t)268435456 - scratch_elems / 2));
    bf16* xq  = cvt;
    bf16* xk  = xq + XN;
    bf16* xv  = xk + XN;
    bf16* wqc = xv + XN;
    bf16* wkc = wqc + WN;
    bf16* wvc = wkc + WN;

    bf16* qws  = (bf16*)d_ws;                  // (B,H,S,D)  bf16
    bf16* kws  = qws + (size_t)BS * DIM;       // (B,H,S,D)  bf16
    bf16* vtws = kws + (size_t)BS * DIM;       // (B,H,D,S)  bf16 (transposed)
    bf16* aws  = vtws + (size_t)BS * DIM;      // (B,S,DIM)  bf16
    bf16* woc  = qws;                          // reuse qws region AFTER attn

    dim3 blk(256);
    cvt_kernel<<<dim3(4096, 6), blk, 0, stream>>>(
        Q, K, V, Wq, Wk, Wv, xq, xk, xv, wqc, wkc, wvc);
    proj_mfma_kernel<<<dim3(DIM / 128, BS / 128, 3), blk, 0, stream>>>(
        xq, xk, xv, wqc, wkc, wvc, qws, kws, vtws);
    attn_kernel<<<dim3(SEQ / QBLK, HEADS, BATCH), dim3(512), 0, stream>>>(
        qws, kws, vtws, weights, aws);
    cvt_wo_kernel<<<dim3(WN / (256 * 8)), blk, 0, stream>>>(Wo, woc);
    oproj_mfma_kernel<<<dim3(DIM / 128, BS / 128), blk, 0, stream>>>(
        aws, woc, bo, out);
}

// Round 8
// 503.361 us; speedup vs baseline: 1.0443x; 1.0443x over previous
//
#include <hip/hip_runtime.h>
#include <hip/hip_bf16.h>

typedef __hip_bfloat16 bf16;
typedef __attribute__((ext_vector_type(8))) short bf16x8;
typedef __attribute__((ext_vector_type(4))) float f32x4;

#define HEADS 16
#define HDIM  64
#define DIM   1024
#define SEQ   2048
#define BATCH 4
#define BS    (BATCH * SEQ)   // 8192
#define SCALE 0.125f          // 1/sqrt(64)
#define CS    0.1803368801111f  // SCALE * log2(e): softmax in exp2 domain

#define EXP2F(x) __builtin_amdgcn_exp2f(x)
#define MFMA16(a, b, c) __builtin_amdgcn_mfma_f32_16x16x32_bf16(a, b, c, 0, 0, 0)

__device__ __forceinline__ void gload_lds16(const void* g, void* l) {
    __builtin_amdgcn_global_load_lds(
        (const __attribute__((address_space(1))) void*)g,
        (__attribute__((address_space(3))) void*)l, 16, 0, 0);
}

__device__ __forceinline__ void cvt8(const float* __restrict__ src, bf16* __restrict__ dst,
                                     size_t i)
{
    float4 f0 = *(const float4*)&src[i];
    float4 f1 = *(const float4*)&src[i + 4];
    union { bf16 h[8]; uint4 u; } pk;
    pk.h[0] = __float2bfloat16(f0.x); pk.h[1] = __float2bfloat16(f0.y);
    pk.h[2] = __float2bfloat16(f0.z); pk.h[3] = __float2bfloat16(f0.w);
    pk.h[4] = __float2bfloat16(f1.x); pk.h[5] = __float2bfloat16(f1.y);
    pk.h[6] = __float2bfloat16(f1.z); pk.h[7] = __float2bfloat16(f1.w);
    *(uint4*)&dst[i] = pk.u;
}

// ---------------------------------------------------------------------------
// Kernel 0a: fp32 -> bf16 for Q,K,V,Wq,Wk,Wv (consumed by proj, which
// completes BEFORE attn overwrites the scratch region in weights-tail).
// ---------------------------------------------------------------------------
__global__ __launch_bounds__(256) void cvt_kernel(
    const float* __restrict__ Q, const float* __restrict__ K, const float* __restrict__ V,
    const float* __restrict__ Wq, const float* __restrict__ Wk, const float* __restrict__ Wv,
    bf16* __restrict__ xq, bf16* __restrict__ xk, bf16* __restrict__ xv,
    bf16* __restrict__ wq, bf16* __restrict__ wk, bf16* __restrict__ wv)
{
    const int seg = blockIdx.y;
    const float* src; bf16* dst; size_t n;
    switch (seg) {
        case 0: src = Q;  dst = xq; n = (size_t)BS * DIM;   break;
        case 1: src = K;  dst = xk; n = (size_t)BS * DIM;   break;
        case 2: src = V;  dst = xv; n = (size_t)BS * DIM;   break;
        case 3: src = Wq; dst = wq; n = (size_t)DIM * DIM;  break;
        case 4: src = Wk; dst = wk; n = (size_t)DIM * DIM;  break;
        default: src = Wv; dst = wv; n = (size_t)DIM * DIM; break;
    }
    size_t i = ((size_t)blockIdx.x * 256 + threadIdx.x) * 8;
    if (i >= n) return;
    cvt8(src, dst, i);
}

// Kernel 0b: Wo fp32 -> bf16, launched AFTER attn into the then-dead qws
// region of d_ws (attn is qws's last reader).
__global__ __launch_bounds__(256) void cvt_wo_kernel(
    const float* __restrict__ Wo, bf16* __restrict__ wo)
{
    size_t i = ((size_t)blockIdx.x * 256 + threadIdx.x) * 8;
    cvt8(Wo, wo, i);
}

// ---------------------------------------------------------------------------
// MFMA GEMM core: 128x128 C-tile of A (row-major, ld=DIM) x B^T (B row-major,
// ld=DIM), K=DIM.  Fragment-linear LDS (see round-2 comment).
// ---------------------------------------------------------------------------
__device__ __forceinline__ void mfma_core_1024(
    const bf16* __restrict__ A, const bf16* __restrict__ B,
    int m0, int n0, bf16* sA, f32x4 acc[4][4])
{
    const int tid = threadIdx.x, lane = tid & 63, wave = tid >> 6;
    const int l15 = lane & 15, lg = lane >> 4;
    const int wr = wave >> 1, wc = wave & 1;
    bf16* sB = sA + 16 * 512;

    const bf16* gsrc = (wave < 2) ? A : B;
    const int   gm0  = (wave < 2) ? m0 : n0;
    bf16*       sdst = (wave < 2) ? sA : sB;
    const int   wv2  = wave & 1;

#define STAGE(k0_) { \
    _Pragma("unroll") for (int u = 0; u < 8; ++u) { \
        const int c = wv2 * 8 + u; \
        const int mg = c >> 1, s = c & 1; \
        gload_lds16(gsrc + (size_t)(gm0 + mg * 16 + l15) * DIM + (k0_) + s * 32 + lg * 8, \
                    sdst + c * 512); \
    } }

    STAGE(0);
#pragma unroll 1
    for (int t = 0; t < DIM / 64; ++t) {
        __syncthreads();
#pragma unroll
        for (int s = 0; s < 2; ++s) {
            bf16x8 af[4], bfr[4];
#pragma unroll
            for (int i = 0; i < 4; ++i)
                af[i] = *(const bf16x8*)(sA + ((wr * 4 + i) * 2 + s) * 512 + lane * 8);
#pragma unroll
            for (int j = 0; j < 4; ++j)
                bfr[j] = *(const bf16x8*)(sB + ((wc * 4 + j) * 2 + s) * 512 + lane * 8);
#pragma unroll
            for (int i = 0; i < 4; ++i)
#pragma unroll
                for (int j = 0; j < 4; ++j)
                    acc[i][j] = MFMA16(af[i], bfr[j], acc[i][j]);
        }
        __syncthreads();
        if (t < DIM / 64 - 1) STAGE((t + 1) * 64);
    }
#undef STAGE
}

// ---------------------------------------------------------------------------
// Kernel 1: QKV projections via MFMA.  Q/K out (B,H,S,D); V out (B,H,D,S).
// ---------------------------------------------------------------------------
__global__ __launch_bounds__(256) void proj_mfma_kernel(
    const bf16* __restrict__ Xq, const bf16* __restrict__ Xk, const bf16* __restrict__ Xv,
    const bf16* __restrict__ Wq, const bf16* __restrict__ Wk, const bf16* __restrict__ Wv,
    bf16* __restrict__ qo, bf16* __restrict__ ko, bf16* __restrict__ vo)
{
    __shared__ alignas(16) bf16 smem[16384];   // 32 KB
    const int z = blockIdx.z;
    const bf16* X = z == 0 ? Xq : z == 1 ? Xk : Xv;
    const bf16* W = z == 0 ? Wq : z == 1 ? Wk : Wv;
    const int m0 = blockIdx.y * 128, n0 = blockIdx.x * 128;
    f32x4 acc[4][4] = {};
    mfma_core_1024(X, W, m0, n0, smem, acc);

    const int tid = threadIdx.x, lane = tid & 63, wave = tid >> 6;
    const int l15 = lane & 15, lg = lane >> 4, wr = wave >> 1, wc = wave & 1;
    const int h = blockIdx.x * 2 + wc;     // 128-wide n-tile spans 2 heads

    if (z != 2) {
        bf16* O = z == 0 ? qo : ko;
#pragma unroll
        for (int i = 0; i < 4; ++i)
#pragma unroll
            for (int r = 0; r < 4; ++r) {
                int m = m0 + wr * 64 + i * 16 + lg * 4 + r;
                int bb = m >> 11, ss = m & (SEQ - 1);
                size_t base = ((size_t)(bb * HEADS + h) * SEQ + ss) * HDIM;
#pragma unroll
                for (int j = 0; j < 4; ++j)
                    O[base + j * 16 + l15] = __float2bfloat16(acc[i][j][r]);
            }
    } else {
#pragma unroll
        for (int i = 0; i < 4; ++i) {
            int s0 = m0 + wr * 64 + i * 16 + lg * 4;
            int bb = s0 >> 11, ss = s0 & (SEQ - 1);
#pragma unroll
            for (int j = 0; j < 4; ++j) {
                int d = j * 16 + l15;
                union { bf16 h4[4]; uint2 u; } pk;
#pragma unroll
                for (int r = 0; r < 4; ++r) pk.h4[r] = __float2bfloat16(acc[i][j][r]);
                *(uint2*)&vo[((size_t)(bb * HEADS + h) * HDIM + d) * SEQ + ss] = pk.u;
            }
        }
    }
}

// ---------------------------------------------------------------------------
// Kernel 2: causal attention, MFMA bf16, swapped QK^T (round-6 structure)
// + LDS DOUBLE-BUFFERING: one barrier per k-tile instead of two.
// Iteration kt reads buf[kt&1]; stores for kt+1 go to buf[(kt+1)&1]; the
// top-of-loop barrier orders last iteration's stores vs this one's reads.
// ---------------------------------------------------------------------------
__global__ __launch_bounds__(256) void attn_kernel(
    const bf16* __restrict__ qws, const bf16* __restrict__ kws, const bf16* __restrict__ vtws,
    float* __restrict__ weights, bf16* __restrict__ attn_out)
{
    __shared__ alignas(16) bf16 Ks[2][4096];
    __shared__ alignas(16) bf16 Vs[2][4096];
    __shared__ alignas(16) bf16 Ps[4096];

    const int tid  = threadIdx.x;
    const int lane = tid & 63;
    const int wave = tid >> 6;
    const int l15  = lane & 15;
    const int lg   = lane >> 4;
    const int qt = (int)gridDim.x - 1 - (int)blockIdx.x;  // heavy blocks first
    const int h  = blockIdx.y, b = blockIdx.z;
    const int bh = b * HEADS + h;
    const int q0 = qt * 64;
    const int qloc = 16 * wave + l15;      // this lane's q row within tile

    const bf16* qbase = qws + (size_t)bh * SEQ * HDIM;
    const bf16* kbase = kws + (size_t)bh * SEQ * HDIM;
    const bf16* vbase = vtws + (size_t)bh * HDIM * SEQ;

    bf16x8 qa0, qa1;
    {
        const bf16* qp = qbase + (size_t)(q0 + qloc) * HDIM + lg * 8;
        qa0 = *(const bf16x8*)qp;
        qa1 = *(const bf16x8*)(qp + 32);
    }

#define LOADK(kt_, r0, r1) { \
    const bf16* rp = kbase + (size_t)((kt_) * 64 + 16 * wave + l15) * HDIM + lg * 8; \
    r0 = *(const uint4*)rp; r1 = *(const uint4*)(rp + 32); }
#define STOREK(bf_, r0, r1) { \
    *(uint4*)&Ks[bf_][((wave * 2 + 0) * 64 + lane) * 8] = r0; \
    *(uint4*)&Ks[bf_][((wave * 2 + 1) * 64 + lane) * 8] = r1; }
#define LOADV(kt_, r0, r1) { \
    const bf16* rp = vbase + (size_t)(16 * wave + l15) * SEQ + (kt_) * 64 + lg * 8; \
    r0 = *(const uint4*)rp; r1 = *(const uint4*)(rp + 32); }
#define STOREV(bf_, r0, r1) { \
    *(uint4*)&Vs[bf_][((wave * 2 + 0) * 64 + lane) * 8] = r0; \
    *(uint4*)&Vs[bf_][((wave * 2 + 1) * 64 + lane) * 8] = r1; }
// swapped: A = K chunk, B = Q  ->  acc[ct][r] = S[q=l15][k=ct*16+lg*4+r]
#define QKT(bf_, acc_) { \
    _Pragma("unroll") \
    for (int ct = 0; ct < 4; ++ct) { \
        bf16x8 b0 = *(const bf16x8*)&Ks[bf_][((ct * 2 + 0) * 64 + lane) * 8]; \
        bf16x8 b1 = *(const bf16x8*)&Ks[bf_][((ct * 2 + 1) * 64 + lane) * 8]; \
        acc_[ct] = MFMA16(b0, qa0, acc_[ct]); \
        acc_[ct] = MFMA16(b1, qa1, acc_[ct]); \
    } }

    // ---- pass 1: online row max / sum-exp2 (scalar per-lane stats) ----
    float m_run = -1e30f;
    float l_run = 0.f;

    {
        uint4 k0, k1;
        LOADK(0, k0, k1);
        STOREK(0, k0, k1);
    }
    for (int kt = 0; kt <= qt; ++kt) {
        __syncthreads();                   // prev stores visible, reads fenced
        const int cur = kt & 1;
        const bool more = kt < qt;
        uint4 nk0, nk1;
        if (more) LOADK(kt + 1, nk0, nk1);
        f32x4 acc[4] = {};
        QKT(cur, acc);
        if (more) STOREK(cur ^ 1, nk0, nk1);
        const bool diag = (kt == qt);
        float t[4][4];
#pragma unroll
        for (int ct = 0; ct < 4; ++ct)
#pragma unroll
            for (int r = 0; r < 4; ++r) {
                float v = acc[ct][r] * CS;
                if (diag && (ct * 16 + lg * 4 + r > qloc)) v = -1e30f;
                t[ct][r] = v;
            }
        float tm = -1e30f;
#pragma unroll
        for (int ct = 0; ct < 4; ++ct)
#pragma unroll
            for (int r = 0; r < 4; ++r) tm = fmaxf(tm, t[ct][r]);
        tm = fmaxf(tm, __shfl_xor(tm, 16));
        tm = fmaxf(tm, __shfl_xor(tm, 32));
        float mn = fmaxf(m_run, tm);
        float ps = 0.f;
#pragma unroll
        for (int ct = 0; ct < 4; ++ct)
#pragma unroll
            for (int r = 0; r < 4; ++r) ps += EXP2F(t[ct][r] - mn);
        ps += __shfl_xor(ps, 16);
        ps += __shfl_xor(ps, 32);
        l_run = l_run * EXP2F(m_run - mn) + ps;
        m_run = mn;
    }

    const float il = 1.0f / l_run;

    __syncthreads();   // pass-1 readers done before pass-2 prologue stores

    // ---- pass 2: weights + PV ----
    {
        uint4 k0, k1, v0, v1;
        LOADK(0, k0, k1);
        LOADV(0, v0, v1);
        STOREK(0, k0, k1);
        STOREV(0, v0, v1);
    }
    f32x4 oacc[4] = {};
    const size_t wrow = ((size_t)bh * SEQ + q0 + qloc) * SEQ;

    for (int kt = 0; kt <= qt; ++kt) {
        __syncthreads();                   // prev stores visible, reads fenced
        const int cur = kt & 1;
        const bool more = kt < qt;
        uint4 nk0, nk1, nv0, nv1;
        if (more) { LOADK(kt + 1, nk0, nk1); LOADV(kt + 1, nv0, nv1); }
        f32x4 acc[4] = {};
        QKT(cur, acc);
        if (more) { STOREK(cur ^ 1, nk0, nk1); STOREV(cur ^ 1, nv0, nv1); }
        const bool diag = (kt == qt);
#pragma unroll
        for (int ct = 0; ct < 4; ++ct) {
            f32x4 w4;
            union { bf16 h4[4]; uint2 u; } pk;
#pragma unroll
            for (int r = 0; r < 4; ++r) {
                float v = acc[ct][r] * CS;
                if (diag && (ct * 16 + lg * 4 + r > qloc)) v = -1e30f;
                float w = EXP2F(v - m_run) * il;
                w4[r] = w;
                pk.h4[r] = __float2bfloat16(w);
            }
            __builtin_nontemporal_store(
                w4, (f32x4*)&weights[wrow + kt * 64 + ct * 16 + lg * 4]);
            // packed P transpose into wave-private LDS (A-fragment layout):
            *(uint2*)&Ps[(((wave * 2 + (ct >> 1)) * 64
                           + ((ct & 1) * 2 + (lg >> 1)) * 16 + l15) * 8
                          + (lg & 1) * 4)] = pk.u;
        }
        // PV: Ps is wave-private; compiler orders ds_write -> ds_read.
        bf16x8 pa0 = *(const bf16x8*)&Ps[((wave * 2 + 0) * 64 + lane) * 8];
        bf16x8 pa1 = *(const bf16x8*)&Ps[((wave * 2 + 1) * 64 + lane) * 8];
#pragma unroll
        for (int td = 0; td < 4; ++td) {
            bf16x8 vb0 = *(const bf16x8*)&Vs[cur][((td * 2 + 0) * 64 + lane) * 8];
            bf16x8 vb1 = *(const bf16x8*)&Vs[cur][((td * 2 + 1) * 64 + lane) * 8];
            oacc[td] = MFMA16(pa0, vb0, oacc[td]);
            oacc[td] = MFMA16(pa1, vb1, oacc[td]);
        }
    }

    // O tile write: (b, s, h*64 + d) bf16  (row q = lg*4+r, col d = td*16+l15)
#pragma unroll
    for (int td = 0; td < 4; ++td)
#pragma unroll
        for (int r = 0; r < 4; ++r) {
            int rowg = q0 + 16 * wave + lg * 4 + r;
            attn_out[((size_t)b * SEQ + rowg) * DIM + h * HDIM + td * 16 + l15]
                = __float2bfloat16(oacc[td][r]);
        }

    // zero-fill masked (upper-triangle) weight columns (streaming NT stores)
    const int zc0 = (qt + 1) * 64;
    if (zc0 < SEQ) {
        const int nc4 = (SEQ - zc0) >> 2;
        const size_t base = ((size_t)bh * SEQ + q0) * SEQ + zc0;
        const f32x4 z = {0.f, 0.f, 0.f, 0.f};
        for (int r = 0; r < 64; ++r)
            for (int c = tid; c < nc4; c += 256)
                __builtin_nontemporal_store(
                    z, (f32x4*)&weights[base + (size_t)r * SEQ + (size_t)c * 4]);
    }
#undef LOADK
#undef STOREK
#undef LOADV
#undef STOREV
#undef QKT
}

// ---------------------------------------------------------------------------
// Kernel 3: output projection via MFMA, fp32 out + bias.
// ---------------------------------------------------------------------------
__global__ __launch_bounds__(256) void oproj_mfma_kernel(
    const bf16* __restrict__ A, const bf16* __restrict__ Wo,
    const float* __restrict__ bo, float* __restrict__ out)
{
    __shared__ alignas(16) bf16 smem[16384];
    const int m0 = blockIdx.y * 128, n0 = blockIdx.x * 128;
    f32x4 acc[4][4] = {};
    mfma_core_1024(A, Wo, m0, n0, smem, acc);

    const int tid = threadIdx.x, lane = tid & 63, wave = tid >> 6;
    const int l15 = lane & 15, lg = lane >> 4, wr = wave >> 1, wc = wave & 1;
    float bv[4];
#pragma unroll
    for (int j = 0; j < 4; ++j) bv[j] = bo[n0 + wc * 64 + j * 16 + l15];
#pragma unroll
    for (int i = 0; i < 4; ++i)
#pragma unroll
        for (int r = 0; r < 4; ++r) {
            int m = m0 + wr * 64 + i * 16 + lg * 4 + r;
#pragma unroll
            for (int j = 0; j < 4; ++j)
                out[(size_t)m * DIM + n0 + wc * 64 + j * 16 + l15] = acc[i][j][r] + bv[j];
        }
}

// ---------------------------------------------------------------------------
extern "C" void kernel_launch(void* const* d_in, const int* in_sizes, int n_in,
                              void* d_out, int out_size, void* d_ws, size_t ws_size,
                              hipStream_t stream)
{
    const float* Q  = (const float*)d_in[0];
    const float* K  = (const float*)d_in[1];
    const float* V  = (const float*)d_in[2];
    const float* Wq = (const float*)d_in[3];
    const float* Wk = (const float*)d_in[4];
    const float* Wv = (const float*)d_in[5];
    const float* Wo = (const float*)d_in[6];
    const float* bo = (const float*)d_in[7];

    float* out     = (float*)d_out;
    float* weights = out + (size_t)BS * DIM;   // 268,435,456 floats

    // Pre-attn bf16 scratch lives in the TAIL of the weights buffer; its only
    // readers (proj_mfma) complete before attn overwrites all of weights.
    const size_t XN = (size_t)BS * DIM;        // 8,388,608
    const size_t WN = (size_t)DIM * DIM;       // 1,048,576
    const size_t scratch_elems = 3 * XN + 3 * WN;   // bf16 elements
    bf16* cvt = (bf16*)(weights + ((size_t)268435456 - scratch_elems / 2));
    bf16* xq  = cvt;
    bf16* xk  = xq + XN;
    bf16* xv  = xk + XN;
    bf16* wqc = xv + XN;
    bf16* wkc = wqc + WN;
    bf16* wvc = wkc + WN;

    bf16* qws  = (bf16*)d_ws;                  // (B,H,S,D)  bf16
    bf16* kws  = qws + (size_t)BS * DIM;       // (B,H,S,D)  bf16
    bf16* vtws = kws + (size_t)BS * DIM;       // (B,H,D,S)  bf16 (transposed)
    bf16* aws  = vtws + (size_t)BS * DIM;      // (B,S,DIM)  bf16
    bf16* woc  = qws;                          // reuse qws region AFTER attn

    dim3 blk(256);
    cvt_kernel<<<dim3(4096, 6), blk, 0, stream>>>(
        Q, K, V, Wq, Wk, Wv, xq, xk, xv, wqc, wkc, wvc);
    proj_mfma_kernel<<<dim3(DIM / 128, BS / 128, 3), blk, 0, stream>>>(
        xq, xk, xv, wqc, wkc, wvc, qws, kws, vtws);
    attn_kernel<<<dim3(SEQ / 64, HEADS, BATCH), blk, 0, stream>>>(
        qws, kws, vtws, weights, aws);
    cvt_wo_kernel<<<dim3(WN / (256 * 8)), blk, 0, stream>>>(Wo, woc);
    oproj_mfma_kernel<<<dim3(DIM / 128, BS / 128), blk, 0, stream>>>(
        aws, woc, bo, out);
}

// Round 9
// 490.299 us; speedup vs baseline: 1.0722x; 1.0266x over previous
//
#include <hip/hip_runtime.h>
#include <hip/hip_bf16.h>

typedef __hip_bfloat16 bf16;
typedef __attribute__((ext_vector_type(8))) short bf16x8;
typedef __attribute__((ext_vector_type(4))) float f32x4;

#define HEADS 16
#define HDIM  64
#define DIM   1024
#define SEQ   2048
#define BATCH 4
#define BS    (BATCH * SEQ)   // 8192
#define SCALE 0.125f          // 1/sqrt(64)
#define CS    0.1803368801111f  // SCALE * log2(e): softmax in exp2 domain

#define EXP2F(x) __builtin_amdgcn_exp2f(x)
#define MFMA16(a, b, c) __builtin_amdgcn_mfma_f32_16x16x32_bf16(a, b, c, 0, 0, 0)

__device__ __forceinline__ void gload_lds16(const void* g, void* l) {
    __builtin_amdgcn_global_load_lds(
        (const __attribute__((address_space(1))) void*)g,
        (__attribute__((address_space(3))) void*)l, 16, 0, 0);
}

__device__ __forceinline__ void cvt8(const float* __restrict__ src, bf16* __restrict__ dst,
                                     size_t i)
{
    float4 f0 = *(const float4*)&src[i];
    float4 f1 = *(const float4*)&src[i + 4];
    union { bf16 h[8]; uint4 u; } pk;
    pk.h[0] = __float2bfloat16(f0.x); pk.h[1] = __float2bfloat16(f0.y);
    pk.h[2] = __float2bfloat16(f0.z); pk.h[3] = __float2bfloat16(f0.w);
    pk.h[4] = __float2bfloat16(f1.x); pk.h[5] = __float2bfloat16(f1.y);
    pk.h[6] = __float2bfloat16(f1.z); pk.h[7] = __float2bfloat16(f1.w);
    *(uint4*)&dst[i] = pk.u;
}

// ---------------------------------------------------------------------------
// Kernel 0a: fp32 -> bf16 for Q,K,V,Wq,Wk,Wv (consumed by proj, which
// completes BEFORE attn overwrites the scratch region in weights-tail).
// ---------------------------------------------------------------------------
__global__ __launch_bounds__(256) void cvt_kernel(
    const float* __restrict__ Q, const float* __restrict__ K, const float* __restrict__ V,
    const float* __restrict__ Wq, const float* __restrict__ Wk, const float* __restrict__ Wv,
    bf16* __restrict__ xq, bf16* __restrict__ xk, bf16* __restrict__ xv,
    bf16* __restrict__ wq, bf16* __restrict__ wk, bf16* __restrict__ wv)
{
    const int seg = blockIdx.y;
    const float* src; bf16* dst; size_t n;
    switch (seg) {
        case 0: src = Q;  dst = xq; n = (size_t)BS * DIM;   break;
        case 1: src = K;  dst = xk; n = (size_t)BS * DIM;   break;
        case 2: src = V;  dst = xv; n = (size_t)BS * DIM;   break;
        case 3: src = Wq; dst = wq; n = (size_t)DIM * DIM;  break;
        case 4: src = Wk; dst = wk; n = (size_t)DIM * DIM;  break;
        default: src = Wv; dst = wv; n = (size_t)DIM * DIM; break;
    }
    size_t i = ((size_t)blockIdx.x * 256 + threadIdx.x) * 8;
    if (i >= n) return;
    cvt8(src, dst, i);
}

// Kernel 0b: Wo fp32 -> bf16, launched AFTER attn into the then-dead qws
// region of d_ws (attn is qws's last reader).
__global__ __launch_bounds__(256) void cvt_wo_kernel(
    const float* __restrict__ Wo, bf16* __restrict__ wo)
{
    size_t i = ((size_t)blockIdx.x * 256 + threadIdx.x) * 8;
    cvt8(Wo, wo, i);
}

// ---------------------------------------------------------------------------
// MFMA GEMM core: 128x128 C-tile of A (row-major, ld=DIM) x B^T (B row-major,
// ld=DIM), K=DIM.  Fragment-linear LDS (see round-2 comment).
// SWAP=false: acc[i][j] entry (lg*4+r, l15) = (A-row m, B-row n)  -> rows=m.
// SWAP=true : operands swapped -> entry (lg*4+r, l15) = (n, m)    -> rows=n,
// i.e. per lane: fixed m = i*16+l15, four consecutive n = j*16+lg*4+r in
// registers -> packed row-major stores in the epilogue.
// ---------------------------------------------------------------------------
template <bool SWAP>
__device__ __forceinline__ void mfma_core_1024(
    const bf16* __restrict__ A, const bf16* __restrict__ B,
    int m0, int n0, bf16* sA, f32x4 acc[4][4])
{
    const int tid = threadIdx.x, lane = tid & 63, wave = tid >> 6;
    const int l15 = lane & 15, lg = lane >> 4;
    const int wr = wave >> 1, wc = wave & 1;
    bf16* sB = sA + 16 * 512;

    const bf16* gsrc = (wave < 2) ? A : B;
    const int   gm0  = (wave < 2) ? m0 : n0;
    bf16*       sdst = (wave < 2) ? sA : sB;
    const int   wv2  = wave & 1;

#define STAGE(k0_) { \
    _Pragma("unroll") for (int u = 0; u < 8; ++u) { \
        const int c = wv2 * 8 + u; \
        const int mg = c >> 1, s = c & 1; \
        gload_lds16(gsrc + (size_t)(gm0 + mg * 16 + l15) * DIM + (k0_) + s * 32 + lg * 8, \
                    sdst + c * 512); \
    } }

    STAGE(0);
#pragma unroll 1
    for (int t = 0; t < DIM / 64; ++t) {
        __syncthreads();
#pragma unroll
        for (int s = 0; s < 2; ++s) {
            bf16x8 af[4], bfr[4];
#pragma unroll
            for (int i = 0; i < 4; ++i)
                af[i] = *(const bf16x8*)(sA + ((wr * 4 + i) * 2 + s) * 512 + lane * 8);
#pragma unroll
            for (int j = 0; j < 4; ++j)
                bfr[j] = *(const bf16x8*)(sB + ((wc * 4 + j) * 2 + s) * 512 + lane * 8);
#pragma unroll
            for (int i = 0; i < 4; ++i)
#pragma unroll
                for (int j = 0; j < 4; ++j) {
                    if (SWAP) acc[i][j] = MFMA16(bfr[j], af[i], acc[i][j]);
                    else      acc[i][j] = MFMA16(af[i], bfr[j], acc[i][j]);
                }
        }
        __syncthreads();
        if (t < DIM / 64 - 1) STAGE((t + 1) * 64);
    }
#undef STAGE
}

// ---------------------------------------------------------------------------
// Kernel 1: QKV projections via MFMA.  Q/K out (B,H,S,D) via SWAPPED core ->
// packed uint2 stores (4 consecutive d per lane).  V out (B,H,D,S) via
// unswapped core (4 consecutive s per lane), packed uint2 stores.
// ---------------------------------------------------------------------------
__global__ __launch_bounds__(256) void proj_mfma_kernel(
    const bf16* __restrict__ Xq, const bf16* __restrict__ Xk, const bf16* __restrict__ Xv,
    const bf16* __restrict__ Wq, const bf16* __restrict__ Wk, const bf16* __restrict__ Wv,
    bf16* __restrict__ qo, bf16* __restrict__ ko, bf16* __restrict__ vo)
{
    __shared__ alignas(16) bf16 smem[16384];   // 32 KB
    const int z = blockIdx.z;
    const bf16* X = z == 0 ? Xq : z == 1 ? Xk : Xv;
    const bf16* W = z == 0 ? Wq : z == 1 ? Wk : Wv;
    const int m0 = blockIdx.y * 128, n0 = blockIdx.x * 128;

    const int tid = threadIdx.x, lane = tid & 63, wave = tid >> 6;
    const int l15 = lane & 15, lg = lane >> 4, wr = wave >> 1, wc = wave & 1;
    const int h = blockIdx.x * 2 + wc;     // 128-wide n-tile spans 2 heads

    f32x4 acc[4][4] = {};
    if (z != 2) {
        mfma_core_1024<true>(X, W, m0, n0, smem, acc);
        // swapped: m = m0+wr*64+i*16+l15 (fixed/lane), n(d) = j*16+lg*4+r
        bf16* O = z == 0 ? qo : ko;
#pragma unroll
        for (int i = 0; i < 4; ++i) {
            int m = m0 + wr * 64 + i * 16 + l15;
            int bb = m >> 11, ss = m & (SEQ - 1);
            size_t base = ((size_t)(bb * HEADS + h) * SEQ + ss) * HDIM;
#pragma unroll
            for (int j = 0; j < 4; ++j) {
                union { bf16 h4[4]; uint2 u; } pk;
#pragma unroll
                for (int r = 0; r < 4; ++r) pk.h4[r] = __float2bfloat16(acc[i][j][r]);
                *(uint2*)&O[base + j * 16 + lg * 4] = pk.u;
            }
        }
    } else {
        mfma_core_1024<false>(X, W, m0, n0, smem, acc);
        // unswapped: s = m0+wr*64+i*16+lg*4+r (4 consecutive), d = j*16+l15
#pragma unroll
        for (int i = 0; i < 4; ++i) {
            int s0 = m0 + wr * 64 + i * 16 + lg * 4;
            int bb = s0 >> 11, ss = s0 & (SEQ - 1);
#pragma unroll
            for (int j = 0; j < 4; ++j) {
                int d = j * 16 + l15;
                union { bf16 h4[4]; uint2 u; } pk;
#pragma unroll
                for (int r = 0; r < 4; ++r) pk.h4[r] = __float2bfloat16(acc[i][j][r]);
                *(uint2*)&vo[((size_t)(bb * HEADS + h) * HDIM + d) * SEQ + ss] = pk.u;
            }
        }
    }
}

// ---------------------------------------------------------------------------
// Kernel 2: causal attention, MFMA bf16, swapped QK^T (round-6 structure,
// single-buffer, 2 barriers/k-tile — best measured config).
// ---------------------------------------------------------------------------
__global__ __launch_bounds__(256) void attn_kernel(
    const bf16* __restrict__ qws, const bf16* __restrict__ kws, const bf16* __restrict__ vtws,
    float* __restrict__ weights, bf16* __restrict__ attn_out)
{
    __shared__ alignas(16) bf16 Ks[4096];
    __shared__ alignas(16) bf16 Vs[4096];
    __shared__ alignas(16) bf16 Ps[4096];

    const int tid  = threadIdx.x;
    const int lane = tid & 63;
    const int wave = tid >> 6;
    const int l15  = lane & 15;
    const int lg   = lane >> 4;
    const int qt = (int)gridDim.x - 1 - (int)blockIdx.x;  // heavy blocks first
    const int h  = blockIdx.y, b = blockIdx.z;
    const int bh = b * HEADS + h;
    const int q0 = qt * 64;
    const int qloc = 16 * wave + l15;      // this lane's q row within tile

    const bf16* qbase = qws + (size_t)bh * SEQ * HDIM;
    const bf16* kbase = kws + (size_t)bh * SEQ * HDIM;
    const bf16* vbase = vtws + (size_t)bh * HDIM * SEQ;

    bf16x8 qa0, qa1;
    {
        const bf16* qp = qbase + (size_t)(q0 + qloc) * HDIM + lg * 8;
        qa0 = *(const bf16x8*)qp;
        qa1 = *(const bf16x8*)(qp + 32);
    }

#define LOADK(kt_, r0, r1) { \
    const bf16* rp = kbase + (size_t)((kt_) * 64 + 16 * wave + l15) * HDIM + lg * 8; \
    r0 = *(const uint4*)rp; r1 = *(const uint4*)(rp + 32); }
#define STOREK(r0, r1) { \
    *(uint4*)&Ks[((wave * 2 + 0) * 64 + lane) * 8] = r0; \
    *(uint4*)&Ks[((wave * 2 + 1) * 64 + lane) * 8] = r1; }
#define LOADV(kt_, r0, r1) { \
    const bf16* rp = vbase + (size_t)(16 * wave + l15) * SEQ + (kt_) * 64 + lg * 8; \
    r0 = *(const uint4*)rp; r1 = *(const uint4*)(rp + 32); }
#define STOREV(r0, r1) { \
    *(uint4*)&Vs[((wave * 2 + 0) * 64 + lane) * 8] = r0; \
    *(uint4*)&Vs[((wave * 2 + 1) * 64 + lane) * 8] = r1; }
// swapped: A = K chunk, B = Q  ->  acc[ct][r] = S[q=l15][k=ct*16+lg*4+r]
#define QKT(acc_) { \
    _Pragma("unroll") \
    for (int ct = 0; ct < 4; ++ct) { \
        bf16x8 b0 = *(const bf16x8*)&Ks[((ct * 2 + 0) * 64 + lane) * 8]; \
        bf16x8 b1 = *(const bf16x8*)&Ks[((ct * 2 + 1) * 64 + lane) * 8]; \
        acc_[ct] = MFMA16(b0, qa0, acc_[ct]); \
        acc_[ct] = MFMA16(b1, qa1, acc_[ct]); \
    } }

    // ---- pass 1: online row max / sum-exp2 (scalar per-lane stats) ----
    float m_run = -1e30f;
    float l_run = 0.f;

    {
        uint4 k0, k1;
        LOADK(0, k0, k1);
        STOREK(k0, k1);
    }
    for (int kt = 0; kt <= qt; ++kt) {
        __syncthreads();
        f32x4 acc[4] = {};
        QKT(acc);
        const bool more = kt < qt;
        uint4 nk0, nk1;
        if (more) LOADK(kt + 1, nk0, nk1);
        const bool diag = (kt == qt);
        float t[4][4];
#pragma unroll
        for (int ct = 0; ct < 4; ++ct)
#pragma unroll
            for (int r = 0; r < 4; ++r) {
                float v = acc[ct][r] * CS;
                if (diag && (ct * 16 + lg * 4 + r > qloc)) v = -1e30f;
                t[ct][r] = v;
            }
        float tm = -1e30f;
#pragma unroll
        for (int ct = 0; ct < 4; ++ct)
#pragma unroll
            for (int r = 0; r < 4; ++r) tm = fmaxf(tm, t[ct][r]);
        tm = fmaxf(tm, __shfl_xor(tm, 16));
        tm = fmaxf(tm, __shfl_xor(tm, 32));
        float mn = fmaxf(m_run, tm);
        float ps = 0.f;
#pragma unroll
        for (int ct = 0; ct < 4; ++ct)
#pragma unroll
            for (int r = 0; r < 4; ++r) ps += EXP2F(t[ct][r] - mn);
        ps += __shfl_xor(ps, 16);
        ps += __shfl_xor(ps, 32);
        l_run = l_run * EXP2F(m_run - mn) + ps;
        m_run = mn;
        __syncthreads();
        if (more) STOREK(nk0, nk1);
    }

    const float il = 1.0f / l_run;

    // ---- pass 2: weights + PV ----
    {
        uint4 k0, k1, v0, v1;
        LOADK(0, k0, k1);
        LOADV(0, v0, v1);
        STOREK(k0, k1);
        STOREV(v0, v1);
    }
    f32x4 oacc[4] = {};
    const size_t wrow = ((size_t)bh * SEQ + q0 + qloc) * SEQ;

    for (int kt = 0; kt <= qt; ++kt) {
        __syncthreads();
        f32x4 acc[4] = {};
        QKT(acc);
        const bool more = kt < qt;
        uint4 nk0, nk1, nv0, nv1;
        if (more) { LOADK(kt + 1, nk0, nk1); LOADV(kt + 1, nv0, nv1); }
        const bool diag = (kt == qt);
#pragma unroll
        for (int ct = 0; ct < 4; ++ct) {
            f32x4 w4;
            union { bf16 h4[4]; uint2 u; } pk;
#pragma unroll
            for (int r = 0; r < 4; ++r) {
                float v = acc[ct][r] * CS;
                if (diag && (ct * 16 + lg * 4 + r > qloc)) v = -1e30f;
                float w = EXP2F(v - m_run) * il;
                w4[r] = w;
                pk.h4[r] = __float2bfloat16(w);
            }
            __builtin_nontemporal_store(
                w4, (f32x4*)&weights[wrow + kt * 64 + ct * 16 + lg * 4]);
            // packed P transpose into wave-private LDS (A-fragment layout):
            *(uint2*)&Ps[(((wave * 2 + (ct >> 1)) * 64
                           + ((ct & 1) * 2 + (lg >> 1)) * 16 + l15) * 8
                          + (lg & 1) * 4)] = pk.u;
        }
        // PV: Ps is wave-private; compiler orders ds_write -> ds_read.
        bf16x8 pa0 = *(const bf16x8*)&Ps[((wave * 2 + 0) * 64 + lane) * 8];
        bf16x8 pa1 = *(const bf16x8*)&Ps[((wave * 2 + 1) * 64 + lane) * 8];
#pragma unroll
        for (int td = 0; td < 4; ++td) {
            bf16x8 vb0 = *(const bf16x8*)&Vs[((td * 2 + 0) * 64 + lane) * 8];
            bf16x8 vb1 = *(const bf16x8*)&Vs[((td * 2 + 1) * 64 + lane) * 8];
            oacc[td] = MFMA16(pa0, vb0, oacc[td]);
            oacc[td] = MFMA16(pa1, vb1, oacc[td]);
        }
        __syncthreads();
        if (more) { STOREK(nk0, nk1); STOREV(nv0, nv1); }
    }

    // O tile write: (b, s, h*64 + d) bf16  (row q = lg*4+r, col d = td*16+l15)
#pragma unroll
    for (int td = 0; td < 4; ++td)
#pragma unroll
        for (int r = 0; r < 4; ++r) {
            int rowg = q0 + 16 * wave + lg * 4 + r;
            attn_out[((size_t)b * SEQ + rowg) * DIM + h * HDIM + td * 16 + l15]
                = __float2bfloat16(oacc[td][r]);
        }

    // zero-fill masked (upper-triangle) weight columns (streaming NT stores)
    const int zc0 = (qt + 1) * 64;
    if (zc0 < SEQ) {
        const int nc4 = (SEQ - zc0) >> 2;
        const size_t base = ((size_t)bh * SEQ + q0) * SEQ + zc0;
        const f32x4 z = {0.f, 0.f, 0.f, 0.f};
        for (int r = 0; r < 64; ++r)
            for (int c = tid; c < nc4; c += 256)
                __builtin_nontemporal_store(
                    z, (f32x4*)&weights[base + (size_t)r * SEQ + (size_t)c * 4]);
    }
#undef LOADK
#undef STOREK
#undef LOADV
#undef STOREV
#undef QKT
}

// ---------------------------------------------------------------------------
// Kernel 3: output projection via SWAPPED MFMA core -> packed float4 stores
// (4 consecutive n per lane) + vectorized bias load.
// ---------------------------------------------------------------------------
__global__ __launch_bounds__(256) void oproj_mfma_kernel(
    const bf16* __restrict__ A, const bf16* __restrict__ Wo,
    const float* __restrict__ bo, float* __restrict__ out)
{
    __shared__ alignas(16) bf16 smem[16384];
    const int m0 = blockIdx.y * 128, n0 = blockIdx.x * 128;
    f32x4 acc[4][4] = {};
    mfma_core_1024<true>(A, Wo, m0, n0, smem, acc);

    const int tid = threadIdx.x, lane = tid & 63, wave = tid >> 6;
    const int l15 = lane & 15, lg = lane >> 4, wr = wave >> 1, wc = wave & 1;
    // swapped: m = m0+wr*64+i*16+l15 (fixed/lane), n = n0+wc*64+j*16+lg*4+r
    f32x4 bv[4];
#pragma unroll
    for (int j = 0; j < 4; ++j)
        bv[j] = *(const f32x4*)&bo[n0 + wc * 64 + j * 16 + lg * 4];
#pragma unroll
    for (int i = 0; i < 4; ++i) {
        int m = m0 + wr * 64 + i * 16 + l15;
#pragma unroll
        for (int j = 0; j < 4; ++j) {
            f32x4 v = acc[i][j] + bv[j];
            *(f32x4*)&out[(size_t)m * DIM + n0 + wc * 64 + j * 16 + lg * 4] = v;
        }
    }
}

// ---------------------------------------------------------------------------
extern "C" void kernel_launch(void* const* d_in, const int* in_sizes, int n_in,
                              void* d_out, int out_size, void* d_ws, size_t ws_size,
                              hipStream_t stream)
{
    const float* Q  = (const float*)d_in[0];
    const float* K  = (const float*)d_in[1];
    const float* V  = (const float*)d_in[2];
    const float* Wq = (const float*)d_in[3];
    const float* Wk = (const float*)d_in[4];
    const float* Wv = (const float*)d_in[5];
    const float* Wo = (const float*)d_in[6];
    const float* bo = (const float*)d_in[7];

    float* out     = (float*)d_out;
    float* weights = out + (size_t)BS * DIM;   // 268,435,456 floats

    // Pre-attn bf16 scratch lives in the TAIL of the weights buffer; its only
    // readers (proj_mfma) complete before attn overwrites all of weights.
    const size_t XN = (size_t)BS * DIM;        // 8,388,608
    const size_t WN = (size_t)DIM * DIM;       // 1,048,576
    const size_t scratch_elems = 3 * XN + 3 * WN;   // bf16 elements
    bf16* cvt = (bf16*)(weights + ((size_t)268435456 - scratch_elems / 2));
    bf16* xq  = cvt;
    bf16* xk  = xq + XN;
    bf16* xv  = xk + XN;
    bf16* wqc = xv + XN;
    bf16* wkc = wqc + WN;
    bf16* wvc = wkc + WN;

    bf16* qws  = (bf16*)d_ws;                  // (B,H,S,D)  bf16
    bf16* kws  = qws + (size_t)BS * DIM;       // (B,H,S,D)  bf16
    bf16* vtws = kws + (size_t)BS * DIM;       // (B,H,D,S)  bf16 (transposed)
    bf16* aws  = vtws + (size_t)BS * DIM;      // (B,S,DIM)  bf16
    bf16* woc  = qws;                          // reuse qws region AFTER attn

    dim3 blk(256);
    cvt_kernel<<<dim3(4096, 6), blk, 0, stream>>>(
        Q, K, V, Wq, Wk, Wv, xq, xk, xv, wqc, wkc, wvc);
    proj_mfma_kernel<<<dim3(DIM / 128, BS / 128, 3), blk, 0, stream>>>(
        xq, xk, xv, wqc, wkc, wvc, qws, kws, vtws);
    attn_kernel<<<dim3(SEQ / 64, HEADS, BATCH), blk, 0, stream>>>(
        qws, kws, vtws, weights, aws);
    cvt_wo_kernel<<<dim3(WN / (256 * 8)), blk, 0, stream>>>(Wo, woc);
    oproj_mfma_kernel<<<dim3(DIM / 128, BS / 128), blk, 0, stream>>>(
        aws, woc, bo, out);
}